// Round 1
// baseline (77.023 us; speedup 1.0000x reference)
//
#include <hip/hip_runtime.h>
#include <cstdint>

// Problem constants (from reference): N=8192, T=1024, CD=4, H=2, KD=VD=8,
// DA=8, AOD=16, LAT=64, OUT=32.

__device__ __forceinline__ float bflo(uint32_t u) { return __uint_as_float(u << 16); }
__device__ __forceinline__ float bfhi(uint32_t u) { return __uint_as_float(u & 0xFFFF0000u); }
__device__ __forceinline__ uint32_t f2bf(float f) {
    uint32_t x = __float_as_uint(f);
    return (x + 0x7FFFu + ((x >> 16) & 1u)) >> 16;   // RNE
}
__device__ __forceinline__ float ftanh(float x) {
    float e = __expf(2.0f * x);
    return 1.0f - 2.0f / (e + 1.0f);   // stable for +-inf of e
}

__global__ __launch_bounds__(256, 4)
void attn_mlp_fused(const float* __restrict__ coord1,
                    const float* __restrict__ coord2,
                    const float* __restrict__ att_coeff,
                    const float* __restrict__ local_coords,
                    const void*  __restrict__ maskp,
                    const float* __restrict__ Wq, const float* __restrict__ Bq,
                    const float* __restrict__ Wk, const float* __restrict__ Bk,
                    const float* __restrict__ Wv, const float* __restrict__ Bv,
                    const float* __restrict__ Wo, const float* __restrict__ Bo,
                    const float* __restrict__ W1, const float* __restrict__ B1,
                    const float* __restrict__ W2, const float* __restrict__ B2,
                    const float* __restrict__ Wt, const float* __restrict__ Bt,
                    float* __restrict__ out)
{
    __shared__ uint4 vq[2048];                 // v table, bf16x2 packed, swizzled (32 KB)
    __shared__ __align__(16) float sc[4][96];  // per-wave scratch: attn[16] | att[16] | act[64]
    __shared__ int mflag;

    const int tid  = threadIdx.x;
    const int lane = tid & 63;
    const int wid  = tid >> 6;

    // ---- detect mask element size: 4-byte (int32/float32 0/1) vs 1-byte (bool) ----
    uint4 mm = ((const uint4*)maskp)[tid];     // first 4 KB of mask buffer
    bool ok = (mm.x <= 1u || mm.x == 0x3F800000u) &&
              (mm.y <= 1u || mm.y == 0x3F800000u) &&
              (mm.z <= 1u || mm.z == 0x3F800000u) &&
              (mm.w <= 1u || mm.w == 0x3F800000u);
    if (tid == 0) mflag = 1;
    __syncthreads();
    if (!ok) atomicAnd(&mflag, 0);

    // ---- stage v = att_coeff @ Wv + Bv into LDS (bf16x2, XOR-swizzled, conflict-free reads) ----
    #pragma unroll
    for (int tt = 0; tt < 4; ++tt) {
        const int t = tid * 4 + tt;
        const float4 a0 = *(const float4*)(att_coeff + t * 8);
        const float4 a1 = *(const float4*)(att_coeff + t * 8 + 4);
        float vr[16];
        #pragma unroll
        for (int o = 0; o < 16; ++o) {
            vr[o] = Bv[o]
                + a0.x * Wv[o]      + a0.y * Wv[16 + o] + a0.z * Wv[32 + o] + a0.w * Wv[48 + o]
                + a1.x * Wv[64 + o] + a1.y * Wv[80 + o] + a1.z * Wv[96 + o] + a1.w * Wv[112 + o];
        }
        #pragma unroll
        for (int h = 0; h < 2; ++h) {
            const int g  = 2 * t + h;
            const int gs = (g & ~7) | ((g ^ (g >> 3)) & 7);   // bijective within 8-group blocks
            uint4 pk;
            pk.x = f2bf(vr[h * 8 + 0]) | (f2bf(vr[h * 8 + 1]) << 16);
            pk.y = f2bf(vr[h * 8 + 2]) | (f2bf(vr[h * 8 + 3]) << 16);
            pk.z = f2bf(vr[h * 8 + 4]) | (f2bf(vr[h * 8 + 5]) << 16);
            pk.w = f2bf(vr[h * 8 + 6]) | (f2bf(vr[h * 8 + 7]) << 16);
            vq[gs] = pk;
        }
    }
    __syncthreads();

    const bool m4 = (mflag != 0);
    const int  l2  = (lane >> 2) & 7;
    const int  bg0 = ((2 * lane)     & ~7) | (((2 * lane)     ^ l2) & 7);  // head 0 v base group
    const int  bg1 = ((2 * lane + 1) & ~7) | (((2 * lane + 1) ^ l2) & 7);  // head 1
    const float rs8 = 0.35355339059327373f;   // 1/sqrt(KD)

    // 1024 blocks x 4 waves; each wave does 2 rows -> 8192 rows
    #pragma unroll
    for (int it = 0; it < 2; ++it) {
        const int n = (blockIdx.x << 3) + (it << 2) + wid;

        const float4 c1 = *(const float4*)(coord1 + n * 4);
        const float4 c2 = *(const float4*)(coord2 + n * 4);

        // q[h,d] = coord1 @ Wq + Bq   (wave-uniform; weights via scalar cache)
        float q[16];
        #pragma unroll
        for (int o = 0; o < 16; ++o)
            q[o] = Bq[o] + c1.x * Wq[o] + c1.y * Wq[16 + o] + c1.z * Wq[32 + o] + c1.w * Wq[48 + o];

        // A[h][c] = sum_d q[h,d]*Wk[c, h*8+d] (scaled);  Bs[h] = q[h,:].Bk[h,:] (scaled)
        float A[2][4], Bs[2];
        #pragma unroll
        for (int h = 0; h < 2; ++h) {
            #pragma unroll
            for (int c = 0; c < 4; ++c) {
                float s = 0.f;
                #pragma unroll
                for (int d = 0; d < 8; ++d) s += q[h * 8 + d] * Wk[c * 16 + h * 8 + d];
                A[h][c] = s * rs8;
            }
            float s2 = 0.f;
            #pragma unroll
            for (int d = 0; d < 8; ++d) s2 += q[h * 8 + d] * Bk[h * 8 + d];
            Bs[h] = s2 * rs8;
        }

        // ---- logits over T, lane-strided: t = i*64 + lane ----
        float lg0[16], lg1[16];
        const float4* lcp = (const float4*)local_coords + (size_t)n * 1024 + lane;
        if (m4) {
            const uint32_t* mp = (const uint32_t*)maskp + (size_t)n * 1024 + lane;
            #pragma unroll
            for (int i = 0; i < 16; ++i) {
                const float4 lc = lcp[i * 64];
                const bool keep = (mp[i * 64] != 0u);
                const float v0 = Bs[0] + lc.x * A[0][0] + lc.y * A[0][1] + lc.z * A[0][2] + lc.w * A[0][3];
                const float v1 = Bs[1] + lc.x * A[1][0] + lc.y * A[1][1] + lc.z * A[1][2] + lc.w * A[1][3];
                lg0[i] = keep ? v0 : -1e30f;
                lg1[i] = keep ? v1 : -1e30f;
            }
        } else {
            const uint8_t* mp = (const uint8_t*)maskp + (size_t)n * 1024 + lane;
            #pragma unroll
            for (int i = 0; i < 16; ++i) {
                const float4 lc = lcp[i * 64];
                const bool keep = (mp[i * 64] != 0u);
                const float v0 = Bs[0] + lc.x * A[0][0] + lc.y * A[0][1] + lc.z * A[0][2] + lc.w * A[0][3];
                const float v1 = Bs[1] + lc.x * A[1][0] + lc.y * A[1][1] + lc.z * A[1][2] + lc.w * A[1][3];
                lg0[i] = keep ? v0 : -1e30f;
                lg1[i] = keep ? v1 : -1e30f;
            }
        }

        // ---- softmax (max, exp, sum); weights left unnormalized, fold 1/sum later ----
        float m0 = lg0[0], m1 = lg1[0];
        #pragma unroll
        for (int i = 1; i < 16; ++i) { m0 = fmaxf(m0, lg0[i]); m1 = fmaxf(m1, lg1[i]); }
        #pragma unroll
        for (int s = 32; s; s >>= 1) {
            m0 = fmaxf(m0, __shfl_xor(m0, s, 64));
            m1 = fmaxf(m1, __shfl_xor(m1, s, 64));
        }
        float s0 = 0.f, s1 = 0.f;
        #pragma unroll
        for (int i = 0; i < 16; ++i) {
            lg0[i] = __expf(lg0[i] - m0); s0 += lg0[i];
            lg1[i] = __expf(lg1[i] - m1); s1 += lg1[i];
        }
        #pragma unroll
        for (int s = 32; s; s >>= 1) {
            s0 += __shfl_xor(s0, s, 64);
            s1 += __shfl_xor(s1, s, 64);
        }
        const float inv0 = 1.0f / s0, inv1 = 1.0f / s1;

        // ---- attn accumulate: p[h*8+d] += e_h[t] * v[t,h,d] (v from LDS, bf16) ----
        float p[16];
        #pragma unroll
        for (int k = 0; k < 16; ++k) p[k] = 0.f;
        #pragma unroll
        for (int i = 0; i < 16; ++i) {
            const uint4 w0 = vq[bg0 + (i << 7)];
            const uint4 w1 = vq[bg1 + (i << 7)];
            const float e0 = lg0[i], e1 = lg1[i];
            p[0]  += e0 * bflo(w0.x); p[1]  += e0 * bfhi(w0.x);
            p[2]  += e0 * bflo(w0.y); p[3]  += e0 * bfhi(w0.y);
            p[4]  += e0 * bflo(w0.z); p[5]  += e0 * bfhi(w0.z);
            p[6]  += e0 * bflo(w0.w); p[7]  += e0 * bfhi(w0.w);
            p[8]  += e1 * bflo(w1.x); p[9]  += e1 * bfhi(w1.x);
            p[10] += e1 * bflo(w1.y); p[11] += e1 * bfhi(w1.y);
            p[12] += e1 * bflo(w1.z); p[13] += e1 * bfhi(w1.z);
            p[14] += e1 * bflo(w1.w); p[15] += e1 * bfhi(w1.w);
        }

        // ---- split butterfly reduce: lane ends owning element e = lane>>2 ----
        {
            const bool h5 = (lane & 32) != 0;
            #pragma unroll
            for (int k = 0; k < 8; ++k) {
                const float snd = h5 ? p[k] : p[k + 8];
                const float kp  = h5 ? p[k + 8] : p[k];
                p[k] = kp + __shfl_xor(snd, 32, 64);
            }
            const bool h4 = (lane & 16) != 0;
            #pragma unroll
            for (int k = 0; k < 4; ++k) {
                const float snd = h4 ? p[k] : p[k + 4];
                const float kp  = h4 ? p[k + 4] : p[k];
                p[k] = kp + __shfl_xor(snd, 16, 64);
            }
            const bool h3 = (lane & 8) != 0;
            #pragma unroll
            for (int k = 0; k < 2; ++k) {
                const float snd = h3 ? p[k] : p[k + 2];
                const float kp  = h3 ? p[k + 2] : p[k];
                p[k] = kp + __shfl_xor(snd, 8, 64);
            }
            const bool h2 = (lane & 4) != 0;
            {
                const float snd = h2 ? p[0] : p[1];
                const float kp  = h2 ? p[1] : p[0];
                p[0] = kp + __shfl_xor(snd, 4, 64);
            }
            p[0] += __shfl_xor(p[0], 2, 64);
            p[0] += __shfl_xor(p[0], 1, 64);
        }
        // normalize and publish attn[e] (e = lane>>2, head = lane>>5)
        if ((lane & 3) == 0)
            sc[wid][lane >> 2] = p[0] * (lane >= 32 ? inv1 : inv0);

        // ---- att[j] = exp(-(attn . Wo[:,j] + Bo[j])), lanes 0..15 ----
        {
            const float4 t0 = *(const float4*)&sc[wid][0];
            const float4 t1 = *(const float4*)&sc[wid][4];
            const float4 t2 = *(const float4*)&sc[wid][8];
            const float4 t3 = *(const float4*)&sc[wid][12];
            if (lane < 16) {
                float acc = Bo[lane];
                acc += t0.x * Wo[0 * 16 + lane]  + t0.y * Wo[1 * 16 + lane]
                     + t0.z * Wo[2 * 16 + lane]  + t0.w * Wo[3 * 16 + lane];
                acc += t1.x * Wo[4 * 16 + lane]  + t1.y * Wo[5 * 16 + lane]
                     + t1.z * Wo[6 * 16 + lane]  + t1.w * Wo[7 * 16 + lane];
                acc += t2.x * Wo[8 * 16 + lane]  + t2.y * Wo[9 * 16 + lane]
                     + t2.z * Wo[10 * 16 + lane] + t2.w * Wo[11 * 16 + lane];
                acc += t3.x * Wo[12 * 16 + lane] + t3.y * Wo[13 * 16 + lane]
                     + t3.z * Wo[14 * 16 + lane] + t3.w * Wo[15 * 16 + lane];
                sc[wid][16 + lane] = __expf(-acc);
            }
        }

        // ---- layer 1: act1[j] = tanh([c1,c2,att] . W1[:,j] + B1[j]), j = lane ----
        {
            const float4 a0 = *(const float4*)&sc[wid][16];
            const float4 a1 = *(const float4*)&sc[wid][20];
            const float4 a2 = *(const float4*)&sc[wid][24];
            const float4 a3 = *(const float4*)&sc[wid][28];
            float acc = B1[lane];
            acc += c1.x * W1[0 * 64 + lane]  + c1.y * W1[1 * 64 + lane]
                 + c1.z * W1[2 * 64 + lane]  + c1.w * W1[3 * 64 + lane];
            acc += c2.x * W1[4 * 64 + lane]  + c2.y * W1[5 * 64 + lane]
                 + c2.z * W1[6 * 64 + lane]  + c2.w * W1[7 * 64 + lane];
            acc += a0.x * W1[8 * 64 + lane]  + a0.y * W1[9 * 64 + lane]
                 + a0.z * W1[10 * 64 + lane] + a0.w * W1[11 * 64 + lane];
            acc += a1.x * W1[12 * 64 + lane] + a1.y * W1[13 * 64 + lane]
                 + a1.z * W1[14 * 64 + lane] + a1.w * W1[15 * 64 + lane];
            acc += a2.x * W1[16 * 64 + lane] + a2.y * W1[17 * 64 + lane]
                 + a2.z * W1[18 * 64 + lane] + a2.w * W1[19 * 64 + lane];
            acc += a3.x * W1[20 * 64 + lane] + a3.y * W1[21 * 64 + lane]
                 + a3.z * W1[22 * 64 + lane] + a3.w * W1[23 * 64 + lane];
            sc[wid][32 + lane] = ftanh(acc);
        }

        // ---- layer 2: act2[j] = tanh(act1 . W2[:,j] + B2[j]) ----
        {
            float acc = B2[lane];
            #pragma unroll
            for (int i = 0; i < 16; ++i) {
                const float4 v4 = *(const float4*)&sc[wid][32 + i * 4];
                acc += v4.x * W2[(i * 4 + 0) * 64 + lane] + v4.y * W2[(i * 4 + 1) * 64 + lane]
                     + v4.z * W2[(i * 4 + 2) * 64 + lane] + v4.w * W2[(i * 4 + 3) * 64 + lane];
            }
            const float a = ftanh(acc);
            // all lanes have finished reading act1 above (in-order DS within wave)
            sc[wid][32 + lane] = a;
        }

        // ---- layer 3: out[o] = tanh(act2 . Wt[:,o] + Bt[o]), lanes 0..31 ----
        if (lane < 32) {
            float acc = Bt[lane];
            #pragma unroll
            for (int i = 0; i < 16; ++i) {
                const float4 v4 = *(const float4*)&sc[wid][32 + i * 4];
                acc += v4.x * Wt[(i * 4 + 0) * 32 + lane] + v4.y * Wt[(i * 4 + 1) * 32 + lane]
                     + v4.z * Wt[(i * 4 + 2) * 32 + lane] + v4.w * Wt[(i * 4 + 3) * 32 + lane];
            }
            out[(size_t)n * 32 + lane] = ftanh(acc);
        }
    }
}

extern "C" void kernel_launch(void* const* d_in, const int* in_sizes, int n_in,
                              void* d_out, int out_size, void* d_ws, size_t ws_size,
                              hipStream_t stream) {
    (void)in_sizes; (void)n_in; (void)out_size; (void)d_ws; (void)ws_size;
    attn_mlp_fused<<<1024, 256, 0, stream>>>(
        (const float*)d_in[0],  (const float*)d_in[1],
        (const float*)d_in[2],  (const float*)d_in[3],
        d_in[4],
        (const float*)d_in[5],  (const float*)d_in[6],
        (const float*)d_in[7],  (const float*)d_in[8],
        (const float*)d_in[9],  (const float*)d_in[10],
        (const float*)d_in[11], (const float*)d_in[12],
        (const float*)d_in[13], (const float*)d_in[14],
        (const float*)d_in[15], (const float*)d_in[16],
        (const float*)d_in[17], (const float*)d_in[18],
        (float*)d_out);
}